// Round 3
// baseline (158.709 us; speedup 1.0000x reference)
//
#include <hip/hip_runtime.h>

// Batched block-diagonal MLP, weights staged PACKED into LDS.
//
// Why: round-2 counters showed both pipes idle (VALUBusy 36%, HBM 21%) at
// 61% occupancy -> per-wave dependency stalls. Weights were s_load'ed
// (wave-uniform indices); SMEM completes out-of-order so every weight use
// forces s_waitcnt lgkmcnt(0), draining the ds_read queue too. Fix: weights
// live in LDS (packed, 12.7 KB), read via uniform-address ds_read_b128
// (broadcast, conflict-free, IN-ORDER on lgkmcnt -> fine-grained waits).
//
// x path (unchanged from round 2, FETCH was near-ideal): each wave owns 64
// rows, stages 16-column chunks through a padded LDS tile (row stride 20
// words -> start bank-quad (5*r+f)&7, coprime -> minimum aliasing), with
// register prefetch of chunk c+1 during chunk c's 512 FMAs. No barriers
// after the single weight-staging barrier.

#define ROWSTRIDE 20               // 16 data + 4 pad floats
#define W_TOTAL   3168             // 2048 Win + 1024 hidden-diag + 96 out
#define XTILE     (64 * ROWSTRIDE) // floats per wave

__global__ __launch_bounds__(512, 6)
void bd_mlp_kernel(const float* __restrict__ x,
                   const float* __restrict__ Win,    // [64][32]
                   const float* __restrict__ Wh,     // [4][32][32]
                   const float* __restrict__ Wout,   // [32][24]
                   float* __restrict__ out,          // [B][24]
                   int B)
{
    __shared__ __align__(16) float smem[W_TOTAL + 8 * XTILE];

    const int tid  = threadIdx.x;
    const int wid  = tid >> 6;
    const int lane = tid & 63;

    // ---- stage packed weights into LDS (once, then one barrier) ----
    for (int i = tid; i < W_TOTAL; i += 512) {
        float v;
        if (i < 2048) {
            v = Win[i];                              // [k][j] as-is
        } else if (i < 3072) {
            int t   = i - 2048;                      // [l][blk][kk][jj]
            int l   = t >> 8;
            int u   = t & 255;
            int blk = u >> 6;
            int kk  = (u >> 3) & 7;
            int jj  = u & 7;
            v = Wh[l * 1024 + (blk * 8 + kk) * 32 + blk * 8 + jj];
        } else {
            int t  = i - 3072;                       // [i][s][c]
            int i8 = t / 12;
            int r  = t - i8 * 12;
            int s  = r / 3;
            int c  = r - s * 3;
            v = Wout[(4 * i8 + s) * 24 + 3 * i8 + c];
        }
        smem[i] = v;
    }
    __syncthreads();

    const float* __restrict__ w_in = smem;           // 2048
    const float* __restrict__ w_h  = smem + 2048;    // 1024
    const float* __restrict__ w_o  = smem + 3072;    // 96
    float* __restrict__ wbuf = smem + W_TOTAL + wid * XTILE;

    const int rowbase = blockIdx.x * 512 + wid * 64;
    const int row     = rowbase + lane;

    float h[32];
#pragma unroll
    for (int j = 0; j < 32; ++j) h[j] = 0.f;

    const bool full = (rowbase + 64 <= B);           // wave-uniform

    if (full) {
        const int r0 = lane >> 2;
        const int f0 = lane & 3;
        const float* __restrict__ gsrc =
            x + (size_t)rowbase * 64 + (size_t)r0 * 64 + f0 * 4;
        float* __restrict__ wdst = wbuf + r0 * ROWSTRIDE + f0 * 4;
        const float* __restrict__ rsrc = wbuf + lane * ROWSTRIDE;

        float4 p0 = *reinterpret_cast<const float4*>(gsrc +    0);
        float4 p1 = *reinterpret_cast<const float4*>(gsrc + 1024);
        float4 p2 = *reinterpret_cast<const float4*>(gsrc + 2048);
        float4 p3 = *reinterpret_cast<const float4*>(gsrc + 3072);

#pragma unroll
        for (int c = 0; c < 4; ++c) {
            *reinterpret_cast<float4*>(wdst + 0 * 16 * ROWSTRIDE) = p0;
            *reinterpret_cast<float4*>(wdst + 1 * 16 * ROWSTRIDE) = p1;
            *reinterpret_cast<float4*>(wdst + 2 * 16 * ROWSTRIDE) = p2;
            *reinterpret_cast<float4*>(wdst + 3 * 16 * ROWSTRIDE) = p3;

            if (c < 3) {
                const float* g = gsrc + (c + 1) * 16;
                p0 = *reinterpret_cast<const float4*>(g +    0);
                p1 = *reinterpret_cast<const float4*>(g + 1024);
                p2 = *reinterpret_cast<const float4*>(g + 2048);
                p3 = *reinterpret_cast<const float4*>(g + 3072);
            }

#pragma unroll
            for (int q = 0; q < 4; ++q) {
                const float4 xv =
                    *reinterpret_cast<const float4*>(rsrc + 4 * q);
                float xk[4] = {xv.x, xv.y, xv.z, xv.w};
                const float4* __restrict__ wp4 = reinterpret_cast<const float4*>(
                    w_in + (c * 16 + q * 4) * 32);
#pragma unroll
                for (int kk = 0; kk < 4; ++kk) {
#pragma unroll
                    for (int m = 0; m < 8; ++m) {
                        float4 w4 = wp4[kk * 8 + m];
                        h[4 * m + 0] = fmaf(xk[kk], w4.x, h[4 * m + 0]);
                        h[4 * m + 1] = fmaf(xk[kk], w4.y, h[4 * m + 1]);
                        h[4 * m + 2] = fmaf(xk[kk], w4.z, h[4 * m + 2]);
                        h[4 * m + 3] = fmaf(xk[kk], w4.w, h[4 * m + 3]);
                    }
                }
            }
        }
    } else if (row < B) {
        const float* __restrict__ xr = x + (size_t)row * 64;
        for (int k = 0; k < 64; ++k) {
            const float xv = xr[k];
            const float* __restrict__ wp = w_in + k * 32;
#pragma unroll
            for (int j = 0; j < 32; ++j) h[j] = fmaf(xv, wp[j], h[j]);
        }
    }

#pragma unroll
    for (int j = 0; j < 32; ++j) h[j] = fmaxf(h[j], 0.f);

    // ---- 4 block-diagonal hidden layers, weights packed [l][blk][kk][jj] ----
#pragma unroll
    for (int l = 0; l < 4; ++l) {
        float hn[32];
#pragma unroll
        for (int blk = 0; blk < 4; ++blk) {
            const float4* __restrict__ wp = reinterpret_cast<const float4*>(
                w_h + l * 256 + blk * 64);
#pragma unroll
            for (int jj = 0; jj < 8; ++jj) hn[blk * 8 + jj] = 0.f;
#pragma unroll
            for (int kk = 0; kk < 8; ++kk) {
                float4 wa = wp[kk * 2 + 0];
                float4 wb = wp[kk * 2 + 1];
                float hk = h[blk * 8 + kk];
                hn[blk * 8 + 0] = fmaf(hk, wa.x, hn[blk * 8 + 0]);
                hn[blk * 8 + 1] = fmaf(hk, wa.y, hn[blk * 8 + 1]);
                hn[blk * 8 + 2] = fmaf(hk, wa.z, hn[blk * 8 + 2]);
                hn[blk * 8 + 3] = fmaf(hk, wa.w, hn[blk * 8 + 3]);
                hn[blk * 8 + 4] = fmaf(hk, wb.x, hn[blk * 8 + 4]);
                hn[blk * 8 + 5] = fmaf(hk, wb.y, hn[blk * 8 + 5]);
                hn[blk * 8 + 6] = fmaf(hk, wb.z, hn[blk * 8 + 6]);
                hn[blk * 8 + 7] = fmaf(hk, wb.w, hn[blk * 8 + 7]);
            }
        }
#pragma unroll
        for (int j = 0; j < 32; ++j) h[j] = fmaxf(hn[j], 0.f);
    }

    // ---- output layer: 8 blocks of 4x3, weights packed [i][s][c] (48 B) ----
    float o[24];
#pragma unroll
    for (int i = 0; i < 8; ++i) {
        const float4* __restrict__ wp =
            reinterpret_cast<const float4*>(w_o + i * 12);
        float4 a = wp[0], b = wp[1], c4 = wp[2];
        float w[12] = {a.x, a.y, a.z, a.w, b.x, b.y, b.z, b.w,
                       c4.x, c4.y, c4.z, c4.w};
#pragma unroll
        for (int c = 0; c < 3; ++c) {
            float acc = 0.f;
#pragma unroll
            for (int s = 0; s < 4; ++s)
                acc = fmaf(h[4 * i + s], w[s * 3 + c], acc);
            o[3 * i + c] = acc;
        }
    }

    if (row < B) {
        float4* __restrict__ o4 =
            reinterpret_cast<float4*>(out) + (size_t)row * 6;
#pragma unroll
        for (int q = 0; q < 6; ++q) {
            o4[q] = make_float4(o[4 * q + 0], o[4 * q + 1],
                                o[4 * q + 2], o[4 * q + 3]);
        }
    }
}

extern "C" void kernel_launch(void* const* d_in, const int* in_sizes, int n_in,
                              void* d_out, int out_size, void* d_ws, size_t ws_size,
                              hipStream_t stream)
{
    const float* x    = (const float*)d_in[0];  // [B,64]
    const float* Win  = (const float*)d_in[1];  // [64,32]
    const float* Wh   = (const float*)d_in[2];  // [4,32,32]
    const float* Wout = (const float*)d_in[3];  // [32,24]
    float* out        = (float*)d_out;          // [B,24]

    int B = in_sizes[0] / 64;
    int blocks = (B + 511) / 512;
    bd_mlp_kernel<<<blocks, 512, 0, stream>>>(x, Win, Wh, Wout, out, B);
}

// Round 4
// 97.225 us; speedup vs baseline: 1.6324x; 1.6324x over previous
//
#include <hip/hip_runtime.h>

// Hybrid MFMA + per-row fp32 batched block-diagonal MLP.
//
// Input layer (64x32 dense, 62% of FMAs and 65% of LDS reads) runs as
// bf16 MFMA 16x16x32: x is loaded DIRECTLY from global in A-fragment
// layout (lane = row l&15, k-octet l>>4; 2 float4 per (m-tile, k-step) ->
// 16 dwordx4 per wave, every 64B line covered exactly once). Win lives in
// 4 per-thread B-fragments loaded once. Output C-layout (col=l&15,
// row=(l>>4)*4+q, verified m89/m91) is transposed to row-per-lane through
// a wave-local XOR-swizzled LDS tile (dword = row*32 + 4*((col>>2)^(row&7))
// + (col&3): writes 2-way, reads perfectly bank-balanced), no barrier
// (same-wave, lgkmcnt-ordered). Hidden/output layers stay exact fp32
// per-row with packed masked weights in LDS (uniform broadcast reads).
// Only the input matmul is bf16: expected absmax ~120 vs threshold 368.

typedef __attribute__((ext_vector_type(8))) short bf16x8;
typedef __attribute__((ext_vector_type(4))) float f32x4;

static __device__ __forceinline__ short f2bf(float f) {
    unsigned u = __builtin_bit_cast(unsigned, f);
    unsigned r = u + 0x7fffu + ((u >> 16) & 1u);   // round-to-nearest-even
    return (short)(r >> 16);
}

#define W_HID   1024
#define W_TOTAL 1120
#define TILE_F  2048   // 64 rows * 32 f32 per wave

__global__ __launch_bounds__(256, 4)
void bd_mlp_kernel(const float* __restrict__ x,
                   const float* __restrict__ Win,    // [64][32]
                   const float* __restrict__ Wh,     // [4][32][32]
                   const float* __restrict__ Wout,   // [32][24]
                   float* __restrict__ out,          // [B][24]
                   int B)
{
    __shared__ __align__(16) float smem[W_TOTAL + 4 * TILE_F];

    const int tid  = threadIdx.x;
    const int wid  = tid >> 6;
    const int lane = tid & 63;
    const int r    = lane & 15;    // row (A) / col (B,C) within 16
    const int g    = lane >> 4;    // k-octet (A,B) / row-quad (C)

    // ---- stage masked hidden/output weights packed into LDS ----
    for (int i = tid; i < W_TOTAL; i += 256) {
        float v;
        if (i < W_HID) {
            int l = i >> 8, u = i & 255;
            int blk = u >> 6, kk = (u >> 3) & 7, jj = u & 7;
            v = Wh[l * 1024 + (blk * 8 + kk) * 32 + blk * 8 + jj];
        } else {
            int t = i - W_HID;
            int i8 = t / 12, rr = t - i8 * 12, s = rr / 3, c = rr - s * 3;
            v = Wout[(4 * i8 + s) * 24 + 3 * i8 + c];
        }
        smem[i] = v;
    }
    __syncthreads();

    const float* __restrict__ w_h = smem;            // [4][4][8][8]
    const float* __restrict__ w_o = smem + W_HID;    // [8][4][3]
    float* __restrict__ tile = smem + W_TOTAL + wid * TILE_F;

    const int rowbase = blockIdx.x * 256 + wid * 64;
    const int row     = rowbase + lane;

    float h[32];

    if (rowbase + 64 <= B) {                         // wave-uniform
        // B-fragments of Win (loaded once, bf16): frag (n,s), elem j =
        // Win[k = s*32 + g*8 + j][col = n*16 + r]
        bf16x8 bw[2][2];
#pragma unroll
        for (int n = 0; n < 2; ++n)
#pragma unroll
            for (int s = 0; s < 2; ++s)
#pragma unroll
                for (int j = 0; j < 8; ++j)
                    bw[n][s][j] = f2bf(Win[(s * 32 + g * 8 + j) * 32 + n * 16 + r]);

        // A (x) direct global loads: lane covers row rowbase+m*16+r,
        // k = s*32 + g*8 + {0..7}  ->  2 float4 per (m,s)
        const float* __restrict__ xb =
            x + (size_t)(rowbase + r) * 64 + g * 8;

        f32x4 acc[4][2];
#pragma unroll
        for (int m = 0; m < 4; ++m)
#pragma unroll
            for (int n = 0; n < 2; ++n)
                acc[m][n] = (f32x4){0.f, 0.f, 0.f, 0.f};

        float4 l0 = *reinterpret_cast<const float4*>(xb + 0);
        float4 l1 = *reinterpret_cast<const float4*>(xb + 4);
        float4 l2 = *reinterpret_cast<const float4*>(xb + 32);
        float4 l3 = *reinterpret_cast<const float4*>(xb + 36);

#pragma unroll
        for (int m = 0; m < 4; ++m) {
            float4 n0, n1, n2, n3;
            if (m < 3) {
                const float* p = xb + (m + 1) * 1024;   // next 16 rows
                n0 = *reinterpret_cast<const float4*>(p + 0);
                n1 = *reinterpret_cast<const float4*>(p + 4);
                n2 = *reinterpret_cast<const float4*>(p + 32);
                n3 = *reinterpret_cast<const float4*>(p + 36);
            }
            bf16x8 a0, a1;
            a0[0] = f2bf(l0.x); a0[1] = f2bf(l0.y);
            a0[2] = f2bf(l0.z); a0[3] = f2bf(l0.w);
            a0[4] = f2bf(l1.x); a0[5] = f2bf(l1.y);
            a0[6] = f2bf(l1.z); a0[7] = f2bf(l1.w);
            a1[0] = f2bf(l2.x); a1[1] = f2bf(l2.y);
            a1[2] = f2bf(l2.z); a1[3] = f2bf(l2.w);
            a1[4] = f2bf(l3.x); a1[5] = f2bf(l3.y);
            a1[6] = f2bf(l3.z); a1[7] = f2bf(l3.w);

#pragma unroll
            for (int n = 0; n < 2; ++n) {
                acc[m][n] = __builtin_amdgcn_mfma_f32_16x16x32_bf16(
                    a0, bw[n][0], acc[m][n], 0, 0, 0);
                acc[m][n] = __builtin_amdgcn_mfma_f32_16x16x32_bf16(
                    a1, bw[n][1], acc[m][n], 0, 0, 0);
            }
            l0 = n0; l1 = n1; l2 = n2; l3 = n3;
        }

        // relu + transpose C-layout -> row-per-lane via XOR-swizzled tile
#pragma unroll
        for (int m = 0; m < 4; ++m)
#pragma unroll
            for (int n = 0; n < 2; ++n)
#pragma unroll
                for (int q = 0; q < 4; ++q) {
                    int rw  = m * 16 + g * 4 + q;
                    int col = n * 16 + r;
                    tile[rw * 32 + 4 * ((col >> 2) ^ (rw & 7)) + (col & 3)] =
                        fmaxf(acc[m][n][q], 0.f);
                }
#pragma unroll
        for (int k4 = 0; k4 < 8; ++k4) {
            float4 v = *reinterpret_cast<const float4*>(
                &tile[lane * 32 + 4 * (k4 ^ (lane & 7))]);
            h[4 * k4 + 0] = v.x; h[4 * k4 + 1] = v.y;
            h[4 * k4 + 2] = v.z; h[4 * k4 + 3] = v.w;
        }
    } else {
        // tail wave (unused for B % 256 == 0): exact fp32 fallback
#pragma unroll
        for (int j = 0; j < 32; ++j) h[j] = 0.f;
        if (row < B) {
            const float* __restrict__ xr = x + (size_t)row * 64;
            for (int k = 0; k < 64; ++k) {
                float xv = xr[k];
#pragma unroll
                for (int j = 0; j < 32; ++j)
                    h[j] = fmaf(xv, Win[k * 32 + j], h[j]);
            }
#pragma unroll
            for (int j = 0; j < 32; ++j) h[j] = fmaxf(h[j], 0.f);
        }
    }

    // ---- 4 block-diagonal hidden layers (exact fp32) ----
#pragma unroll
    for (int l = 0; l < 4; ++l) {
#pragma unroll
        for (int blk = 0; blk < 4; ++blk) {
            const float4* __restrict__ wp =
                reinterpret_cast<const float4*>(w_h + l * 256 + blk * 64);
            float hn[8];
#pragma unroll
            for (int jj = 0; jj < 8; ++jj) hn[jj] = 0.f;
#pragma unroll
            for (int kk = 0; kk < 8; ++kk) {
                float4 wa = wp[kk * 2 + 0];
                float4 wb = wp[kk * 2 + 1];
                float hk = h[blk * 8 + kk];
                hn[0] = fmaf(hk, wa.x, hn[0]);
                hn[1] = fmaf(hk, wa.y, hn[1]);
                hn[2] = fmaf(hk, wa.z, hn[2]);
                hn[3] = fmaf(hk, wa.w, hn[3]);
                hn[4] = fmaf(hk, wb.x, hn[4]);
                hn[5] = fmaf(hk, wb.y, hn[5]);
                hn[6] = fmaf(hk, wb.z, hn[6]);
                hn[7] = fmaf(hk, wb.w, hn[7]);
            }
#pragma unroll
            for (int jj = 0; jj < 8; ++jj)
                h[blk * 8 + jj] = fmaxf(hn[jj], 0.f);
        }
    }

    // ---- output layer: 8 blocks of 4x3 ----
    float o[24];
#pragma unroll
    for (int i = 0; i < 8; ++i) {
        const float4* __restrict__ wp =
            reinterpret_cast<const float4*>(w_o + i * 12);
        float4 a = wp[0], b = wp[1], c4 = wp[2];
        float w[12] = {a.x, a.y, a.z, a.w, b.x, b.y, b.z, b.w,
                       c4.x, c4.y, c4.z, c4.w};
#pragma unroll
        for (int c = 0; c < 3; ++c) {
            float acc2 = 0.f;
#pragma unroll
            for (int s = 0; s < 4; ++s)
                acc2 = fmaf(h[4 * i + s], w[s * 3 + c], acc2);
            o[3 * i + c] = acc2;
        }
    }

    if (row < B) {
        float4* __restrict__ o4 =
            reinterpret_cast<float4*>(out) + (size_t)row * 6;
#pragma unroll
        for (int q = 0; q < 6; ++q)
            o4[q] = make_float4(o[4 * q + 0], o[4 * q + 1],
                                o[4 * q + 2], o[4 * q + 3]);
    }
}

extern "C" void kernel_launch(void* const* d_in, const int* in_sizes, int n_in,
                              void* d_out, int out_size, void* d_ws, size_t ws_size,
                              hipStream_t stream)
{
    const float* x    = (const float*)d_in[0];  // [B,64]
    const float* Win  = (const float*)d_in[1];  // [64,32]
    const float* Wh   = (const float*)d_in[2];  // [4,32,32]
    const float* Wout = (const float*)d_in[3];  // [32,24]
    float* out        = (float*)d_out;          // [B,24]

    int B = in_sizes[0] / 64;
    int blocks = (B + 255) / 256;
    bd_mlp_kernel<<<blocks, 256, 0, stream>>>(x, Win, Wh, Wout, out, B);
}

// Round 5
// 92.978 us; speedup vs baseline: 1.7069x; 1.0457x over previous
//
#include <hip/hip_runtime.h>

// Full-MFMA batched block-diagonal MLP, transposed chaining, zero LDS.
//
// Everything computes D = W^T · h^T (batch lives in the MFMA *column* dim).
// The 16x16x16 C/D layout (col=lane&15, row=4*(lane>>4)+q) is IDENTICAL to
// the 16x16x16 B-operand layout (col=lane&15, k=4*(lane>>4)+j), so layers
// chain with only an in-lane relu + f32->f16 convert: no LDS, no shuffles,
// no transpose, no barriers.
//
// A repack pre-kernel writes all weights (masked block-diagonal, transposed,
// zero-padded) into per-lane A-fragment order in d_ws as f16; the main
// kernel reads them back as 24 coalesced vector loads (L2-resident).
// x is loaded directly from global in B-fragment layout (16 dwordx4/lane,
// every byte of the wave's 64 rows covered exactly once); outputs stored
// directly from the final C tiles (row*96B + 16g, 16B-aligned).

typedef _Float16 f16;
typedef __attribute__((ext_vector_type(4))) _Float16 f16x4;
typedef __attribute__((ext_vector_type(8))) _Float16 f16x8;
typedef __attribute__((ext_vector_type(4))) float f32x4;

#define WS_WH  2048   // f16 offset of hidden-layer frags
#define WS_WO  6144   // f16 offset of output-layer frags
#define WS_TOT 7168

// ---- repack: weights -> per-lane MFMA A-fragments (masked, f16) ----
__global__ void repack_kernel(const float* __restrict__ Win,   // [64][32]
                              const float* __restrict__ Wh,    // [4][32][32]
                              const float* __restrict__ Wout,  // [32][24]
                              f16* __restrict__ ws)
{
    for (int i = threadIdx.x; i < WS_TOT; i += 256) {
        float val;
        if (i < WS_WH) {
            // WIN: frag fi = h*2+s (16x16x32 A): elem j, lane l:
            // A[m][k=32s+8g+j] = Win[k][16h+m]
            int fi = i >> 9, rest = i & 511;
            int l = rest >> 3, j = rest & 7;
            int h = fi >> 1, s = fi & 1;
            int g = l >> 4, m = l & 15;
            int k = 32 * s + 8 * g + j;
            val = Win[k * 32 + 16 * h + m];
        } else if (i < WS_WO) {
            // WH: frag fi = t*4+h*2+s (16x16x16 A): elem j:
            // A[m][k=16s+4g+j] = mask(k,col)*Wh[t][k][col], col=16h+m
            int t2 = i - WS_WH;
            int fi = t2 >> 8, rest = t2 & 255;
            int l = rest >> 2, j = rest & 3;
            int t = fi >> 2, h = (fi >> 1) & 1, s = fi & 1;
            int g = l >> 4, m = l & 15;
            int k = 16 * s + 4 * g + j, col = 16 * h + m;
            val = ((k >> 3) == (col >> 3)) ? Wh[t * 1024 + k * 32 + col] : 0.f;
        } else {
            // WO: frag fi = h*2+s: cols 24..31 zero-padded;
            // keep if (k>>2) == col/3 (kron(eye(8), ones(4,3)))
            int t2 = i - WS_WO;
            int fi = t2 >> 8, rest = t2 & 255;
            int l = rest >> 2, j = rest & 3;
            int h = fi >> 1, s = fi & 1;
            int g = l >> 4, m = l & 15;
            int k = 16 * s + 4 * g + j, col = 16 * h + m;
            val = (col < 24 && (k >> 2) == (col / 3)) ? Wout[k * 24 + col] : 0.f;
        }
        ws[i] = (f16)val;
    }
}

__global__ __launch_bounds__(256, 3)
void bd_mlp_kernel(const float* __restrict__ x,
                   const f16* __restrict__ ws,
                   const float* __restrict__ Win,
                   const float* __restrict__ Wh,
                   const float* __restrict__ Wout,
                   float* __restrict__ out,
                   int B)
{
    const int tid  = threadIdx.x;
    const int wid  = tid >> 6;
    const int lane = tid & 63;
    const int g    = lane >> 4;
    const int b    = lane & 15;

    const int rowbase = blockIdx.x * 256 + wid * 64;

    // ---- weight fragments (coalesced vector loads, L2-resident) ----
    f16x8 wina[2][2];
#pragma unroll
    for (int h = 0; h < 2; ++h)
#pragma unroll
        for (int s = 0; s < 2; ++s)
            wina[h][s] = __builtin_bit_cast(f16x8,
                *reinterpret_cast<const float4*>(ws + (h * 2 + s) * 512 + lane * 8));

    f16x4 wha[4][2][2];
#pragma unroll
    for (int t = 0; t < 4; ++t)
#pragma unroll
        for (int h = 0; h < 2; ++h)
#pragma unroll
            for (int s = 0; s < 2; ++s)
                wha[t][h][s] = __builtin_bit_cast(f16x4,
                    *reinterpret_cast<const float2*>(
                        ws + WS_WH + (t * 4 + h * 2 + s) * 256 + lane * 4));

    f16x4 woa[2][2];
#pragma unroll
    for (int h = 0; h < 2; ++h)
#pragma unroll
        for (int s = 0; s < 2; ++s)
            woa[h][s] = __builtin_bit_cast(f16x4,
                *reinterpret_cast<const float2*>(
                    ws + WS_WO + (h * 2 + s) * 256 + lane * 4));

    const f32x4 zero = {0.f, 0.f, 0.f, 0.f};

    if (rowbase + 64 <= B) {
        // ---- x in B-fragment layout: lane (g,b), chain c, kstep s:
        // elems j=0..7 = x[rowbase+16c+b][32s+8g+j]  (two float4)
        const float* __restrict__ xb =
            x + (size_t)(rowbase + b) * 64 + 8 * g;

        f16x8 bx[4][2];
#pragma unroll
        for (int c = 0; c < 4; ++c)
#pragma unroll
            for (int s = 0; s < 2; ++s) {
                const float* p = xb + c * 1024 + s * 32;
                float4 u0 = *reinterpret_cast<const float4*>(p);
                float4 u1 = *reinterpret_cast<const float4*>(p + 4);
                f16x8 v;
                v[0] = (f16)u0.x; v[1] = (f16)u0.y;
                v[2] = (f16)u0.z; v[3] = (f16)u0.w;
                v[4] = (f16)u1.x; v[5] = (f16)u1.y;
                v[6] = (f16)u1.z; v[7] = (f16)u1.w;
                bx[c][s] = v;
            }

        // ---- input layer: D = Win^T x^T (two 16-row hidden tiles) ----
        f16x4 hb[4][2];
#pragma unroll
        for (int c = 0; c < 4; ++c) {
            f32x4 t0 = __builtin_amdgcn_mfma_f32_16x16x32_f16(
                wina[0][0], bx[c][0], zero, 0, 0, 0);
            t0 = __builtin_amdgcn_mfma_f32_16x16x32_f16(
                wina[0][1], bx[c][1], t0, 0, 0, 0);
            f32x4 t1 = __builtin_amdgcn_mfma_f32_16x16x32_f16(
                wina[1][0], bx[c][0], zero, 0, 0, 0);
            t1 = __builtin_amdgcn_mfma_f32_16x16x32_f16(
                wina[1][1], bx[c][1], t1, 0, 0, 0);
#pragma unroll
            for (int j = 0; j < 4; ++j) {
                hb[c][0][j] = (f16)fmaxf(t0[j], 0.f);
                hb[c][1][j] = (f16)fmaxf(t1[j], 0.f);
            }
        }

        // ---- 4 hidden layers: C rows (4g+q) == next B k-elems (4g+j) ----
#pragma unroll
        for (int t = 0; t < 4; ++t) {
#pragma unroll
            for (int c = 0; c < 4; ++c) {
                f32x4 n0 = __builtin_amdgcn_mfma_f32_16x16x16f16(
                    wha[t][0][0], hb[c][0], zero, 0, 0, 0);
                n0 = __builtin_amdgcn_mfma_f32_16x16x16f16(
                    wha[t][0][1], hb[c][1], n0, 0, 0, 0);
                f32x4 n1 = __builtin_amdgcn_mfma_f32_16x16x16f16(
                    wha[t][1][0], hb[c][0], zero, 0, 0, 0);
                n1 = __builtin_amdgcn_mfma_f32_16x16x16f16(
                    wha[t][1][1], hb[c][1], n1, 0, 0, 0);
#pragma unroll
                for (int j = 0; j < 4; ++j) {
                    hb[c][0][j] = (f16)fmaxf(n0[j], 0.f);
                    hb[c][1][j] = (f16)fmaxf(n1[j], 0.f);
                }
            }
        }

        // ---- output layer (24 cols, padded to 32) + direct store ----
#pragma unroll
        for (int c = 0; c < 4; ++c) {
            f32x4 o0 = __builtin_amdgcn_mfma_f32_16x16x16f16(
                woa[0][0], hb[c][0], zero, 0, 0, 0);
            o0 = __builtin_amdgcn_mfma_f32_16x16x16f16(
                woa[0][1], hb[c][1], o0, 0, 0, 0);
            f32x4 o1 = __builtin_amdgcn_mfma_f32_16x16x16f16(
                woa[1][0], hb[c][0], zero, 0, 0, 0);
            o1 = __builtin_amdgcn_mfma_f32_16x16x16f16(
                woa[1][1], hb[c][1], o1, 0, 0, 0);

            const size_t R = (size_t)(rowbase + 16 * c + b);
            float* op = out + R * 24;
            *reinterpret_cast<float4*>(op + 4 * g) =
                make_float4(o0[0], o0[1], o0[2], o0[3]);
            if (g < 2) {
                *reinterpret_cast<float4*>(op + 16 + 4 * g) =
                    make_float4(o1[0], o1[1], o1[2], o1[3]);
            }
        }
    } else {
        // tail fallback (unused for B % 256 == 0): exact fp32 per row
        const int row = rowbase + lane;
        if (row < B) {
            float h[32];
#pragma unroll
            for (int j = 0; j < 32; ++j) h[j] = 0.f;
            const float* __restrict__ xr = x + (size_t)row * 64;
            for (int k = 0; k < 64; ++k) {
                float xv = xr[k];
#pragma unroll
                for (int j = 0; j < 32; ++j)
                    h[j] = fmaf(xv, Win[k * 32 + j], h[j]);
            }
#pragma unroll
            for (int j = 0; j < 32; ++j) h[j] = fmaxf(h[j], 0.f);
            for (int t = 0; t < 4; ++t) {
                float hn[32];
                for (int j = 0; j < 32; ++j) {
                    float acc = 0.f;
                    int blk = j >> 3;
                    for (int k = 0; k < 8; ++k)
                        acc = fmaf(h[blk * 8 + k],
                                   Wh[t * 1024 + (blk * 8 + k) * 32 + j], acc);
                    hn[j] = fmaxf(acc, 0.f);
                }
                for (int j = 0; j < 32; ++j) h[j] = hn[j];
            }
            for (int cth = 0; cth < 24; ++cth) {
                int i8 = cth / 3;
                float acc = 0.f;
                for (int s = 0; s < 4; ++s)
                    acc = fmaf(h[4 * i8 + s], Wout[(4 * i8 + s) * 24 + cth], acc);
                out[(size_t)row * 24 + cth] = acc;
            }
        }
    }
}

extern "C" void kernel_launch(void* const* d_in, const int* in_sizes, int n_in,
                              void* d_out, int out_size, void* d_ws, size_t ws_size,
                              hipStream_t stream)
{
    const float* x    = (const float*)d_in[0];  // [B,64]
    const float* Win  = (const float*)d_in[1];  // [64,32]
    const float* Wh   = (const float*)d_in[2];  // [4,32,32]
    const float* Wout = (const float*)d_in[3];  // [32,24]
    float* out        = (float*)d_out;          // [B,24]
    f16* ws           = (f16*)d_ws;

    int B = in_sizes[0] / 64;

    repack_kernel<<<1, 256, 0, stream>>>(Win, Wh, Wout, ws);

    int blocks = (B + 255) / 256;
    bd_mlp_kernel<<<blocks, 256, 0, stream>>>(x, ws, Win, Wh, Wout, out, B);
}

// Round 6
// 90.264 us; speedup vs baseline: 1.7583x; 1.0301x over previous
//
#include <hip/hip_runtime.h>

// Full-MFMA batched block-diagonal MLP + LDS-staged x (contiguous HBM reads).
//
// Round-5 analysis: direct-to-fragment x loads are strided (64 lanes x 16B
// -> 32 cache lines/instr, 32B used per line). Fix: stage x via
// global_load_lds (width 16) with PRE-SWIZZLED per-lane global source and
// linear LDS destination (guide G15/rule 21): LDS[r][Gs] = x[r][Gs^(r&7)]
// at 16-B granule granularity. Each staging instruction covers full 64-B
// lines (1 KB contiguous per instr). Fragment reads use ds_read_b128 at
// granule (2g+8s+h)^(b&7): per-16-lane phase max 2-way bank alias (free).
// Wave-local only -> no barriers. Compute chain identical to round 5
// (all-f16 MFMA, transposed chaining, C-rows == next B-k-elems).

typedef _Float16 f16;
typedef __attribute__((ext_vector_type(4))) _Float16 f16x4;
typedef __attribute__((ext_vector_type(8))) _Float16 f16x8;
typedef __attribute__((ext_vector_type(4))) float f32x4;

#define WS_WH  2048
#define WS_WO  6144
#define WS_TOT 7168

// ---- repack: weights -> per-lane MFMA A-fragments (masked, f16) ----
__global__ void repack_kernel(const float* __restrict__ Win,   // [64][32]
                              const float* __restrict__ Wh,    // [4][32][32]
                              const float* __restrict__ Wout,  // [32][24]
                              f16* __restrict__ ws)
{
    for (int i = threadIdx.x; i < WS_TOT; i += 256) {
        float val;
        if (i < WS_WH) {
            int fi = i >> 9, rest = i & 511;
            int l = rest >> 3, j = rest & 7;
            int h = fi >> 1, s = fi & 1;
            int g = l >> 4, m = l & 15;
            int k = 32 * s + 8 * g + j;
            val = Win[k * 32 + 16 * h + m];
        } else if (i < WS_WO) {
            int t2 = i - WS_WH;
            int fi = t2 >> 8, rest = t2 & 255;
            int l = rest >> 2, j = rest & 3;
            int t = fi >> 2, h = (fi >> 1) & 1, s = fi & 1;
            int g = l >> 4, m = l & 15;
            int k = 16 * s + 4 * g + j, col = 16 * h + m;
            val = ((k >> 3) == (col >> 3)) ? Wh[t * 1024 + k * 32 + col] : 0.f;
        } else {
            int t2 = i - WS_WO;
            int fi = t2 >> 8, rest = t2 & 255;
            int l = rest >> 2, j = rest & 3;
            int h = fi >> 1, s = fi & 1;
            int g = l >> 4, m = l & 15;
            int k = 16 * s + 4 * g + j, col = 16 * h + m;
            val = (col < 24 && (k >> 2) == (col / 3)) ? Wout[k * 24 + col] : 0.f;
        }
        ws[i] = (f16)val;
    }
}

__global__ __launch_bounds__(256, 4)
void bd_mlp_kernel(const float* __restrict__ x,
                   const f16* __restrict__ ws,
                   const float* __restrict__ Win,
                   const float* __restrict__ Wh,
                   const float* __restrict__ Wout,
                   float* __restrict__ out,
                   int B)
{
    __shared__ __align__(16) float lds[4][2048];   // 8 KB per wave

    const int tid  = threadIdx.x;
    const int wid  = tid >> 6;
    const int lane = tid & 63;
    const int g    = lane >> 4;
    const int b    = lane & 15;

    const int rowbase = blockIdx.x * 128 + wid * 32;   // 32 rows per wave
    float* __restrict__ tile = lds[wid];

    const f32x4 zero = {0.f, 0.f, 0.f, 0.f};

    if (rowbase + 32 <= B) {
        // ---- stage x: contiguous 1-KB bursts, source granule-swizzled ----
        // LDS slot (row r, granule Gs) <- x[rowbase+r][granule Gs ^ (r&7)]
#pragma unroll
        for (int j = 0; j < 8; ++j) {
            const int r  = 4 * j + (lane >> 4);
            const int gs = (lane & 15) ^ (r & 7);
            const float* src = x + (size_t)(rowbase + r) * 64 + gs * 4;
            __builtin_amdgcn_global_load_lds(
                (const __attribute__((address_space(1))) void*)src,
                (__attribute__((address_space(3))) void*)(tile + j * 256),
                16, 0, 0);
        }

        // ---- weight fragments (overlap staging latency; L2-resident) ----
        f16x8 wina[2][2];
#pragma unroll
        for (int h = 0; h < 2; ++h)
#pragma unroll
            for (int s = 0; s < 2; ++s)
                wina[h][s] = __builtin_bit_cast(f16x8,
                    *reinterpret_cast<const float4*>(
                        ws + (h * 2 + s) * 512 + lane * 8));

        f16x4 wha[4][2][2];
#pragma unroll
        for (int t = 0; t < 4; ++t)
#pragma unroll
            for (int h = 0; h < 2; ++h)
#pragma unroll
                for (int s = 0; s < 2; ++s)
                    wha[t][h][s] = __builtin_bit_cast(f16x4,
                        *reinterpret_cast<const float2*>(
                            ws + WS_WH + (t * 4 + h * 2 + s) * 256 + lane * 4));

        f16x4 woa[2][2];
#pragma unroll
        for (int h = 0; h < 2; ++h)
#pragma unroll
            for (int s = 0; s < 2; ++s)
                woa[h][s] = __builtin_bit_cast(f16x4,
                    *reinterpret_cast<const float2*>(
                        ws + WS_WO + (h * 2 + s) * 256 + lane * 4));

        asm volatile("s_waitcnt vmcnt(0)" ::: "memory");

#pragma unroll
        for (int c = 0; c < 2; ++c) {
            const int r = 16 * c + b;
            // fragment reads: granule G = 2g+8s+h, stored at G^(b&7)
            f16x8 bx[2];
#pragma unroll
            for (int s = 0; s < 2; ++s) {
                float4 u0 = *reinterpret_cast<const float4*>(
                    tile + r * 64 + 4 * ((2 * g + 8 * s + 0) ^ (b & 7)));
                float4 u1 = *reinterpret_cast<const float4*>(
                    tile + r * 64 + 4 * ((2 * g + 8 * s + 1) ^ (b & 7)));
                f16x8 v;
                v[0] = (f16)u0.x; v[1] = (f16)u0.y;
                v[2] = (f16)u0.z; v[3] = (f16)u0.w;
                v[4] = (f16)u1.x; v[5] = (f16)u1.y;
                v[6] = (f16)u1.z; v[7] = (f16)u1.w;
                bx[s] = v;
            }

            // input layer
            f32x4 t0 = __builtin_amdgcn_mfma_f32_16x16x32_f16(
                wina[0][0], bx[0], zero, 0, 0, 0);
            t0 = __builtin_amdgcn_mfma_f32_16x16x32_f16(
                wina[0][1], bx[1], t0, 0, 0, 0);
            f32x4 t1 = __builtin_amdgcn_mfma_f32_16x16x32_f16(
                wina[1][0], bx[0], zero, 0, 0, 0);
            t1 = __builtin_amdgcn_mfma_f32_16x16x32_f16(
                wina[1][1], bx[1], t1, 0, 0, 0);

            f16x4 hb0, hb1;
#pragma unroll
            for (int j = 0; j < 4; ++j) {
                hb0[j] = (f16)fmaxf(t0[j], 0.f);
                hb1[j] = (f16)fmaxf(t1[j], 0.f);
            }

            // 4 block-diagonal hidden layers
#pragma unroll
            for (int t = 0; t < 4; ++t) {
                f32x4 n0 = __builtin_amdgcn_mfma_f32_16x16x16f16(
                    wha[t][0][0], hb0, zero, 0, 0, 0);
                n0 = __builtin_amdgcn_mfma_f32_16x16x16f16(
                    wha[t][0][1], hb1, n0, 0, 0, 0);
                f32x4 n1 = __builtin_amdgcn_mfma_f32_16x16x16f16(
                    wha[t][1][0], hb0, zero, 0, 0, 0);
                n1 = __builtin_amdgcn_mfma_f32_16x16x16f16(
                    wha[t][1][1], hb1, n1, 0, 0, 0);
#pragma unroll
                for (int j = 0; j < 4; ++j) {
                    hb0[j] = (f16)fmaxf(n0[j], 0.f);
                    hb1[j] = (f16)fmaxf(n1[j], 0.f);
                }
            }

            // output layer + direct store
            f32x4 o0 = __builtin_amdgcn_mfma_f32_16x16x16f16(
                woa[0][0], hb0, zero, 0, 0, 0);
            o0 = __builtin_amdgcn_mfma_f32_16x16x16f16(
                woa[0][1], hb1, o0, 0, 0, 0);
            f32x4 o1 = __builtin_amdgcn_mfma_f32_16x16x16f16(
                woa[1][0], hb0, zero, 0, 0, 0);
            o1 = __builtin_amdgcn_mfma_f32_16x16x16f16(
                woa[1][1], hb1, o1, 0, 0, 0);

            float* op = out + (size_t)(rowbase + r) * 24;
            *reinterpret_cast<float4*>(op + 4 * g) =
                make_float4(o0[0], o0[1], o0[2], o0[3]);
            if (g < 2) {
                *reinterpret_cast<float4*>(op + 16 + 4 * g) =
                    make_float4(o1[0], o1[1], o1[2], o1[3]);
            }
        }
    } else {
        // tail fallback (unused for B % 128 == 0): exact fp32 per row
        const int row = rowbase + lane;
        if (lane < 32 && row < B) {
            float h[32];
#pragma unroll
            for (int j = 0; j < 32; ++j) h[j] = 0.f;
            const float* __restrict__ xr = x + (size_t)row * 64;
            for (int k = 0; k < 64; ++k) {
                float xv = xr[k];
#pragma unroll
                for (int j = 0; j < 32; ++j)
                    h[j] = fmaf(xv, Win[k * 32 + j], h[j]);
            }
#pragma unroll
            for (int j = 0; j < 32; ++j) h[j] = fmaxf(h[j], 0.f);
            for (int t = 0; t < 4; ++t) {
                float hn[32];
                for (int j = 0; j < 32; ++j) {
                    float acc = 0.f;
                    int blk = j >> 3;
                    for (int k = 0; k < 8; ++k)
                        acc = fmaf(h[blk * 8 + k],
                                   Wh[t * 1024 + (blk * 8 + k) * 32 + j], acc);
                    hn[j] = fmaxf(acc, 0.f);
                }
                for (int j = 0; j < 32; ++j) h[j] = hn[j];
            }
            for (int cth = 0; cth < 24; ++cth) {
                int i8 = cth / 3;
                float acc = 0.f;
                for (int s = 0; s < 4; ++s)
                    acc = fmaf(h[4 * i8 + s], Wout[(4 * i8 + s) * 24 + cth], acc);
                out[(size_t)row * 24 + cth] = acc;
            }
        }
    }
}

extern "C" void kernel_launch(void* const* d_in, const int* in_sizes, int n_in,
                              void* d_out, int out_size, void* d_ws, size_t ws_size,
                              hipStream_t stream)
{
    const float* x    = (const float*)d_in[0];  // [B,64]
    const float* Win  = (const float*)d_in[1];  // [64,32]
    const float* Wh   = (const float*)d_in[2];  // [4,32,32]
    const float* Wout = (const float*)d_in[3];  // [32,24]
    float* out        = (float*)d_out;          // [B,24]
    f16* ws           = (f16*)d_ws;

    int B = in_sizes[0] / 64;

    repack_kernel<<<1, 256, 0, stream>>>(Win, Wh, Wout, ws);

    int blocks = (B + 127) / 128;
    bd_mlp_kernel<<<blocks, 256, 0, stream>>>(x, ws, Win, Wh, Wout, out, B);
}

// Round 8
// 67.307 us; speedup vs baseline: 2.3580x; 1.3411x over previous
//
#include <hip/hip_runtime.h>

// Persistent-wave, double-buffered, full-MFMA batched block-diagonal MLP.
//
// Round-6 diagnosis: one-shot blocks serialize load->vmcnt(0)->compute->exit
// and re-load weights every block -> latency-bound at ~4.1 TB/s. Fix:
// 1024 blocks; each wave owns 8 tiles of 32 rows. Weights load ONCE.
// LDS double-buffer (2 x 8KB per wave): stage tiles 0,1; per iteration wait
// a COUNTED vmcnt (8 first / 12 steady / 4 last; per tile = 8 stage loads +
// 4 store instrs, vmcnt retires in issue order), ds_read tile i, lgkmcnt(0),
// then stage tile i+2 into the freed buffer. Staging loads stay in flight
// across compute; vmcnt never drains to 0 in steady state.
//
// Staging (round 6 scheme): global_load_lds width 16, linear LDS dst,
// PRE-SWIZZLED global source (granule gs = (lane&15) ^ (r&7)); fragment
// ds_read_b128 at granule (2g+8s+h)^(b&7) -> <=2-way bank alias (free).
// Compute chain (round 5): all-f16 MFMA, transposed chaining
// (C rows 4g+q == next layer's B k-elems 4g+j), relu+cvt in-lane only.
//
// Round-7 fix: nontemporal stores go through native ext_vector f32x4*
// (__builtin_nontemporal_store rejects HIP_vector_type float4*).

typedef _Float16 f16;
typedef __attribute__((ext_vector_type(4))) _Float16 f16x4;
typedef __attribute__((ext_vector_type(8))) _Float16 f16x8;
typedef __attribute__((ext_vector_type(4))) float f32x4;

#define WS_WH  2048
#define WS_WO  6144
#define WS_TOT 7168

#define WAITV(N) asm volatile("s_waitcnt vmcnt(" #N ")" ::: "memory")

// ---- repack: weights -> per-lane MFMA A-fragments (masked, f16) ----
__global__ void repack_kernel(const float* __restrict__ Win,   // [64][32]
                              const float* __restrict__ Wh,    // [4][32][32]
                              const float* __restrict__ Wout,  // [32][24]
                              f16* __restrict__ ws)
{
    int i = blockIdx.x * 256 + threadIdx.x;
    if (i >= WS_TOT) return;
    float val;
    if (i < WS_WH) {
        int fi = i >> 9, rest = i & 511;
        int l = rest >> 3, j = rest & 7;
        int h = fi >> 1, s = fi & 1;
        int g = l >> 4, m = l & 15;
        int k = 32 * s + 8 * g + j;
        val = Win[k * 32 + 16 * h + m];
    } else if (i < WS_WO) {
        int t2 = i - WS_WH;
        int fi = t2 >> 8, rest = t2 & 255;
        int l = rest >> 2, j = rest & 3;
        int t = fi >> 2, h = (fi >> 1) & 1, s = fi & 1;
        int g = l >> 4, m = l & 15;
        int k = 16 * s + 4 * g + j, col = 16 * h + m;
        val = ((k >> 3) == (col >> 3)) ? Wh[t * 1024 + k * 32 + col] : 0.f;
    } else {
        int t2 = i - WS_WO;
        int fi = t2 >> 8, rest = t2 & 255;
        int l = rest >> 2, j = rest & 3;
        int h = fi >> 1, s = fi & 1;
        int g = l >> 4, m = l & 15;
        int k = 16 * s + 4 * g + j, col = 16 * h + m;
        val = (col < 24 && (k >> 2) == (col / 3)) ? Wout[k * 24 + col] : 0.f;
    }
    ws[i] = (f16)val;
}

__global__ __launch_bounds__(256, 2)
void bd_mlp_kernel(const float* __restrict__ x,
                   const f16* __restrict__ ws,
                   const float* __restrict__ Win,
                   const float* __restrict__ Wh,
                   const float* __restrict__ Wout,
                   float* __restrict__ out,
                   int B)
{
    __shared__ __align__(16) float lds[4][2][2048];   // 2 x 8KB per wave

    const int tid  = threadIdx.x;
    const int wid  = tid >> 6;
    const int lane = tid & 63;
    const int g    = lane >> 4;
    const int b    = lane & 15;

    const int wave_id = blockIdx.x * 4 + wid;
    const int nwaves  = gridDim.x * 4;
    const int ntiles  = B >> 5;               // 32-row tiles

    // ---- weight fragments, loaded once (L2-resident) ----
    f16x8 wina[2][2];
#pragma unroll
    for (int h = 0; h < 2; ++h)
#pragma unroll
        for (int s = 0; s < 2; ++s)
            wina[h][s] = __builtin_bit_cast(f16x8,
                *reinterpret_cast<const f32x4*>(
                    ws + (h * 2 + s) * 512 + lane * 8));

    f16x4 wha[4][2][2];
#pragma unroll
    for (int t = 0; t < 4; ++t)
#pragma unroll
        for (int h = 0; h < 2; ++h)
#pragma unroll
            for (int s = 0; s < 2; ++s)
                wha[t][h][s] = __builtin_bit_cast(f16x4,
                    *reinterpret_cast<const float2*>(
                        ws + WS_WH + (t * 4 + h * 2 + s) * 256 + lane * 4));

    f16x4 woa[2][2];
#pragma unroll
    for (int h = 0; h < 2; ++h)
#pragma unroll
        for (int s = 0; s < 2; ++s)
            woa[h][s] = __builtin_bit_cast(f16x4,
                *reinterpret_cast<const float2*>(
                    ws + WS_WO + (h * 2 + s) * 256 + lane * 4));

    const f32x4 zero = {0.f, 0.f, 0.f, 0.f};

    int nt = 0;
    if (wave_id < ntiles) nt = (ntiles - wave_id - 1) / nwaves + 1;

    auto STAGE = [&](int bufi, int tile) {
        float* tb = &lds[wid][bufi][0];
        const int rowbase = tile << 5;
#pragma unroll
        for (int j = 0; j < 8; ++j) {
            const int r  = 4 * j + (lane >> 4);
            const int gs = (lane & 15) ^ (r & 7);
            const float* src = x + (size_t)(rowbase + r) * 64 + gs * 4;
            __builtin_amdgcn_global_load_lds(
                (const __attribute__((address_space(1))) void*)src,
                (__attribute__((address_space(3))) void*)(tb + j * 256),
                16, 0, 0);
        }
    };

    if (nt > 0) {
        STAGE(0, wave_id);
        if (nt > 1) STAGE(1, wave_id + nwaves);

        for (int i = 0; i < nt; ++i) {
            // counted waits: per tile = 8 stage loads + 4 store instrs,
            // vmcnt retires in issue order (m135).
            if (i == 0)           { if (nt > 1) WAITV(8); else WAITV(0); }
            else if (i + 1 == nt) WAITV(4);
            else                  WAITV(12);
            __builtin_amdgcn_sched_barrier(0);

            const float* tb = &lds[wid][i & 1][0];
            const int rowbase = (wave_id + i * nwaves) << 5;

            // all fragment reads for this tile (must precede re-stage)
            f32x4 raw[2][2][2];
#pragma unroll
            for (int c = 0; c < 2; ++c)
#pragma unroll
                for (int s = 0; s < 2; ++s)
#pragma unroll
                    for (int hh = 0; hh < 2; ++hh)
                        raw[c][s][hh] = *reinterpret_cast<const f32x4*>(
                            tb + (16 * c + b) * 64 +
                            4 * ((2 * g + 8 * s + hh) ^ (b & 7)));
            asm volatile("s_waitcnt lgkmcnt(0)" ::: "memory");
            __builtin_amdgcn_sched_barrier(0);

            if (i + 2 < nt) STAGE(i & 1, wave_id + (i + 2) * nwaves);

#pragma unroll
            for (int c = 0; c < 2; ++c) {
                f16x8 bx[2];
#pragma unroll
                for (int s = 0; s < 2; ++s) {
                    f32x4 u0 = raw[c][s][0];
                    f32x4 u1 = raw[c][s][1];
                    f16x8 v;
                    v[0] = (f16)u0[0]; v[1] = (f16)u0[1];
                    v[2] = (f16)u0[2]; v[3] = (f16)u0[3];
                    v[4] = (f16)u1[0]; v[5] = (f16)u1[1];
                    v[6] = (f16)u1[2]; v[7] = (f16)u1[3];
                    bx[s] = v;
                }

                // input layer
                f32x4 t0 = __builtin_amdgcn_mfma_f32_16x16x32_f16(
                    wina[0][0], bx[0], zero, 0, 0, 0);
                t0 = __builtin_amdgcn_mfma_f32_16x16x32_f16(
                    wina[0][1], bx[1], t0, 0, 0, 0);
                f32x4 t1 = __builtin_amdgcn_mfma_f32_16x16x32_f16(
                    wina[1][0], bx[0], zero, 0, 0, 0);
                t1 = __builtin_amdgcn_mfma_f32_16x16x32_f16(
                    wina[1][1], bx[1], t1, 0, 0, 0);

                f16x4 hb0, hb1;
#pragma unroll
                for (int j = 0; j < 4; ++j) {
                    hb0[j] = (f16)fmaxf(t0[j], 0.f);
                    hb1[j] = (f16)fmaxf(t1[j], 0.f);
                }

                // 4 block-diagonal hidden layers
#pragma unroll
                for (int t = 0; t < 4; ++t) {
                    f32x4 n0 = __builtin_amdgcn_mfma_f32_16x16x16f16(
                        wha[t][0][0], hb0, zero, 0, 0, 0);
                    n0 = __builtin_amdgcn_mfma_f32_16x16x16f16(
                        wha[t][0][1], hb1, n0, 0, 0, 0);
                    f32x4 n1 = __builtin_amdgcn_mfma_f32_16x16x16f16(
                        wha[t][1][0], hb0, zero, 0, 0, 0);
                    n1 = __builtin_amdgcn_mfma_f32_16x16x16f16(
                        wha[t][1][1], hb1, n1, 0, 0, 0);
#pragma unroll
                    for (int j = 0; j < 4; ++j) {
                        hb0[j] = (f16)fmaxf(n0[j], 0.f);
                        hb1[j] = (f16)fmaxf(n1[j], 0.f);
                    }
                }

                // output layer + nontemporal store (native vector type)
                f32x4 o0 = __builtin_amdgcn_mfma_f32_16x16x16f16(
                    woa[0][0], hb0, zero, 0, 0, 0);
                o0 = __builtin_amdgcn_mfma_f32_16x16x16f16(
                    woa[0][1], hb1, o0, 0, 0, 0);
                f32x4 o1 = __builtin_amdgcn_mfma_f32_16x16x16f16(
                    woa[1][0], hb0, zero, 0, 0, 0);
                o1 = __builtin_amdgcn_mfma_f32_16x16x16f16(
                    woa[1][1], hb1, o1, 0, 0, 0);

                float* op = out + (size_t)(rowbase + 16 * c + b) * 24;
                __builtin_nontemporal_store(
                    o0, reinterpret_cast<f32x4*>(op + 4 * g));
                if (g < 2) {
                    __builtin_nontemporal_store(
                        o1, reinterpret_cast<f32x4*>(op + 16 + 4 * g));
                }
            }
        }
    }

    // ---- tail rows (B % 32 != 0; unused for B = 1M) ----
    if (blockIdx.x == 0 && wid == 0) {
        for (int row = (ntiles << 5) + lane; row < B; row += 64) {
            float h[32];
#pragma unroll
            for (int j = 0; j < 32; ++j) h[j] = 0.f;
            const float* __restrict__ xr = x + (size_t)row * 64;
            for (int k = 0; k < 64; ++k) {
                float xv = xr[k];
#pragma unroll
                for (int j = 0; j < 32; ++j)
                    h[j] = fmaf(xv, Win[k * 32 + j], h[j]);
            }
#pragma unroll
            for (int j = 0; j < 32; ++j) h[j] = fmaxf(h[j], 0.f);
            for (int t = 0; t < 4; ++t) {
                float hn[32];
                for (int j = 0; j < 32; ++j) {
                    float acc = 0.f;
                    int blk = j >> 3;
                    for (int k = 0; k < 8; ++k)
                        acc = fmaf(h[blk * 8 + k],
                                   Wh[t * 1024 + (blk * 8 + k) * 32 + j], acc);
                    hn[j] = fmaxf(acc, 0.f);
                }
                for (int j = 0; j < 32; ++j) h[j] = hn[j];
            }
            for (int cth = 0; cth < 24; ++cth) {
                int i8 = cth / 3;
                float acc = 0.f;
                for (int s = 0; s < 4; ++s)
                    acc = fmaf(h[4 * i8 + s], Wout[(4 * i8 + s) * 24 + cth], acc);
                out[(size_t)row * 24 + cth] = acc;
            }
        }
    }
}

extern "C" void kernel_launch(void* const* d_in, const int* in_sizes, int n_in,
                              void* d_out, int out_size, void* d_ws, size_t ws_size,
                              hipStream_t stream)
{
    const float* x    = (const float*)d_in[0];  // [B,64]
    const float* Win  = (const float*)d_in[1];  // [64,32]
    const float* Wh   = (const float*)d_in[2];  // [4,32,32]
    const float* Wout = (const float*)d_in[3];  // [32,24]
    float* out        = (float*)d_out;          // [B,24]
    f16* ws           = (f16*)d_ws;

    int B = in_sizes[0] / 64;

    repack_kernel<<<(WS_TOT + 255) / 256, 256, 0, stream>>>(Win, Wh, Wout, ws);

    bd_mlp_kernel<<<1024, 256, 0, stream>>>(x, ws, Win, Wh, Wout, out, B);
}